// Round 3
// baseline (431.407 us; speedup 1.0000x reference)
//
#include <hip/hip_runtime.h>
#include <math.h>

// AttnBlock: GroupNorm(32) -> q,k,v 1x1 -> spatial attention -> proj -> resid.
// Round 3: key-split flash attention (2 halves -> 512 blocks, 2/CU) + merge
// kernel; qkv/proj staging vectorized to float4; coalesced q/k bf16 stores.

#define BB 4
#define CCH 256
#define NSP 4096
#define EPSV 1e-5f
#define ATTN_SCALE 0.0625f  // 256^-0.5
#define RSQRT2 0.70710678118654752440f
#define KSPLIT 2
#define TILES_PER_HALF 32   // 4096 / 64 / KSPLIT

typedef __attribute__((ext_vector_type(8))) short bf16x8;
typedef __attribute__((ext_vector_type(4))) short bf16x4;
typedef __attribute__((ext_vector_type(4))) float f32x4;

__device__ __forceinline__ short f2bf(float f) {
  union { float f; unsigned u; } a; a.f = f;
  unsigned r = a.u + 0x7fffu + ((a.u >> 16) & 1u);  // RTN-even
  return (short)(r >> 16);
}

// ---------------- GroupNorm ----------------
__global__ __launch_bounds__(256) void gn_kernel(
    const float* __restrict__ x, const float* __restrict__ gw,
    const float* __restrict__ gb, float* __restrict__ h) {
  int b = blockIdx.x >> 5;
  int g = blockIdx.x & 31;
  size_t base = ((size_t)b * CCH + (size_t)g * 8) * NSP;
  const float4* xv = (const float4*)(x + base);
  int tid = threadIdx.x;
  float s = 0.f, ss = 0.f;
  for (int i = tid; i < 8192; i += 256) {
    float4 v = xv[i];
    s += (v.x + v.y) + (v.z + v.w);
    ss += (v.x * v.x + v.y * v.y) + (v.z * v.z + v.w * v.w);
  }
#pragma unroll
  for (int off = 32; off > 0; off >>= 1) {
    s += __shfl_down(s, off, 64);
    ss += __shfl_down(ss, off, 64);
  }
  __shared__ float rs[4], rss[4], stat[2];
  int wv = tid >> 6;
  if ((tid & 63) == 0) { rs[wv] = s; rss[wv] = ss; }
  __syncthreads();
  if (tid == 0) {
    float S = rs[0] + rs[1] + rs[2] + rs[3];
    float SS = rss[0] + rss[1] + rss[2] + rss[3];
    float mean = S * (1.f / 32768.f);
    float var = SS * (1.f / 32768.f) - mean * mean;
    stat[0] = mean;
    stat[1] = rsqrtf(var + EPSV);
  }
  __syncthreads();
  float mean = stat[0], rstd = stat[1];
  float4* hv = (float4*)(h + base);
  for (int i = tid; i < 8192; i += 256) {
    int c = g * 8 + (i >> 10);
    float a = gw[c] * rstd;
    float bb = gb[c] - mean * a;
    float4 v = xv[i];
    float4 o;
    o.x = v.x * a + bb; o.y = v.y * a + bb;
    o.z = v.z * a + bb; o.w = v.w * a + bb;
    hv[i] = o;
  }
}

// ---------------- QKV: fp32 GEMM, bf16 outputs in MFMA-friendly layouts ----
__global__ __launch_bounds__(256) void qkv_kernel(
    const float* __restrict__ h,
    const float* __restrict__ Wq, const float* __restrict__ bq,
    const float* __restrict__ Wk, const float* __restrict__ bk,
    const float* __restrict__ Wv, const float* __restrict__ bv,
    short* __restrict__ qo, short* __restrict__ ko, short* __restrict__ vo) {
  __shared__ __align__(16) float Ws[32][64];
  __shared__ __align__(16) float Hs[32][64];
  __shared__ __align__(16) float Ts[64][68];
  int n0 = blockIdx.x * 64;
  int d0 = blockIdx.y * 64;
  int b = blockIdx.z & 3;
  int op = blockIdx.z >> 2;
  const float* W = (op == 0) ? Wq : (op == 1) ? Wk : Wv;
  const float* bias = (op == 0) ? bq : (op == 1) ? bk : bv;
  const float* hb = h + (size_t)b * CCH * NSP;
  int tid = threadIdx.x;
  int tx = tid & 15, ty = tid >> 4;
  int srow = tid >> 4, sc4 = tid & 15;  // float4 staging: 16 rows/iter
  float acc[4][4] = {};
  for (int c0 = 0; c0 < CCH; c0 += 32) {
#pragma unroll
    for (int i = 0; i < 2; ++i) {
      int row = srow + 16 * i;
      *(float4*)&Ws[row][sc4 * 4] =
          *(const float4*)&W[(size_t)(c0 + row) * CCH + d0 + sc4 * 4];
      *(float4*)&Hs[row][sc4 * 4] =
          *(const float4*)&hb[(size_t)(c0 + row) * NSP + n0 + sc4 * 4];
    }
    __syncthreads();
    for (int cc = 0; cc < 32; ++cc) {
      float4 w4 = *(const float4*)&Ws[cc][ty * 4];
      float4 h4 = *(const float4*)&Hs[cc][tx * 4];
      const float wr[4] = {w4.x, w4.y, w4.z, w4.w};
      const float hr[4] = {h4.x, h4.y, h4.z, h4.w};
#pragma unroll
      for (int i = 0; i < 4; ++i)
#pragma unroll
        for (int j = 0; j < 4; ++j) acc[i][j] += wr[i] * hr[j];
    }
    __syncthreads();
  }
  if (op == 2) {  // v: [c][n] bf16, direct coalesced store
    short* ob = vo + (size_t)b * CCH * NSP;
#pragma unroll
    for (int i = 0; i < 4; ++i) {
      int d = d0 + ty * 4 + i;
      float bi = bias[d];
      bf16x4 r;
      r[0] = f2bf(acc[i][0] + bi); r[1] = f2bf(acc[i][1] + bi);
      r[2] = f2bf(acc[i][2] + bi); r[3] = f2bf(acc[i][3] + bi);
      *(bf16x4*)(ob + (size_t)d * NSP + n0 + tx * 4) = r;
    }
  } else {  // q/k: transpose to [n][c] bf16 (q pre-scaled)
    float sc = (op == 0) ? ATTN_SCALE : 1.f;
#pragma unroll
    for (int i = 0; i < 4; ++i) {
      int d = d0 + ty * 4 + i;
      float bi = bias[d];
#pragma unroll
      for (int j = 0; j < 4; ++j) Ts[tx * 4 + j][ty * 4 + i] = (acc[i][j] + bi) * sc;
    }
    __syncthreads();
    short* ob = ((op == 0) ? qo : ko) + (size_t)b * NSP * CCH;
#pragma unroll
    for (int it = 0; it < 2; ++it) {
      int idx = tid + 256 * it;
      int row = idx >> 3, c8 = (idx & 7) * 8;  // 8 threads cover 128B per row
      float4 f0 = *(float4*)&Ts[row][c8];
      float4 f1 = *(float4*)&Ts[row][c8 + 4];
      bf16x8 r;
      r[0] = f2bf(f0.x); r[1] = f2bf(f0.y); r[2] = f2bf(f0.z); r[3] = f2bf(f0.w);
      r[4] = f2bf(f1.x); r[5] = f2bf(f1.y); r[6] = f2bf(f1.z); r[7] = f2bf(f1.w);
      *(bf16x8*)(ob + (size_t)(n0 + row) * CCH + d0 + c8) = r;
    }
  }
}

// ---------------- flash attention, bf16 MFMA, key-split partials ----------
// q,k: [b][n][c] bf16 (q pre-scaled); v: [b][c][n] bf16.
// Block: 64 queries x 2048 keys (half kh). Writes unnormalized partial O
// [kh][b][c][n] fp32 + m,l stats [kh][b][n].
__global__ __launch_bounds__(256) void attn_kernel(
    const short* __restrict__ q, const short* __restrict__ k,
    const short* __restrict__ v, float* __restrict__ po,
    float* __restrict__ pm, float* __restrict__ pl) {
  __shared__ __align__(16) unsigned char smem[73728];
  short* Ks = (short*)smem;            // [64 m][256 c], swizzled
  short* Vs = (short*)(smem + 32768);  // [256 c][64 m], swizzled
  short* Ps = (short*)(smem + 65536);  // [4 w][16 n][64 m], swizzled
  float* Fo = (float*)smem;            // epilogue [256 c][68], aliases Ks+Vs

  int bx = blockIdx.x;
  int b = bx & 3;
  int n0 = ((bx >> 2) & 63) << 6;
  int kh = bx >> 8;  // key half 0/1
  const short* qb = q + (size_t)b * NSP * CCH;
  const short* kb = k + (size_t)b * NSP * CCH;
  const short* vb = v + (size_t)b * CCH * NSP;
  int tid = threadIdx.x;
  int w = tid >> 6, lane = tid & 63, quad = lane >> 4, l16 = lane & 15;

  int krow0 = tid >> 5, kch = tid & 31;
  int vrow0 = tid >> 3, vch = tid & 7;
  int koff = (kch ^ (krow0 & 7)) * 8;
  int voff = (vch ^ (vrow0 & 7)) * 8;

  // ---- stage Q (into Vs region), extract A-frags into registers ----
  {
    const short* qp = qb + (size_t)(n0 + krow0) * CCH + kch * 8;
#pragma unroll
    for (int i = 0; i < 8; ++i) {
      bf16x8 t = *(const bf16x8*)(qp + (size_t)i * 8 * CCH);
      *(bf16x8*)(Vs + (krow0 + 8 * i) * 256 + koff) = t;
    }
  }
  __syncthreads();
  bf16x8 a_q[8];
  {
    int row = w * 16 + l16;
#pragma unroll
    for (int kc = 0; kc < 8; ++kc)
      a_q[kc] = *(bf16x8*)(Vs + row * 256 + (((kc * 4 + quad) ^ (row & 7)) * 8));
  }
  // ---- prefetch first tile of this half ----
  int mbase = kh * TILES_PER_HALF * 64;
  bf16x8 kreg[8], vreg[8];
  {
    const short* kp = kb + (size_t)(mbase + krow0) * CCH + kch * 8;
    const short* vp = vb + (size_t)vrow0 * NSP + mbase + vch * 8;
#pragma unroll
    for (int i = 0; i < 8; ++i) kreg[i] = *(const bf16x8*)(kp + (size_t)i * 8 * CCH);
#pragma unroll
    for (int i = 0; i < 8; ++i) vreg[i] = *(const bf16x8*)(vp + (size_t)i * 32 * NSP);
  }
  __syncthreads();
#pragma unroll
  for (int i = 0; i < 8; ++i) *(bf16x8*)(Ks + (krow0 + 8 * i) * 256 + koff) = kreg[i];
#pragma unroll
  for (int i = 0; i < 8; ++i) *(bf16x8*)(Vs + (vrow0 + 32 * i) * 64 + voff) = vreg[i];
  __syncthreads();

  f32x4 accO[16];
#pragma unroll
  for (int cb = 0; cb < 16; ++cb) accO[cb] = (f32x4){0.f, 0.f, 0.f, 0.f};
  float m_run[4] = {-1e30f, -1e30f, -1e30f, -1e30f};
  float l_run[4] = {0.f, 0.f, 0.f, 0.f};

#pragma unroll 1
  for (int t = 0; t < TILES_PER_HALF; ++t) {
    if (t < TILES_PER_HALF - 1) {
      int m0 = mbase + (t + 1) * 64;
      const short* kp = kb + (size_t)(m0 + krow0) * CCH + kch * 8;
      const short* vp = vb + (size_t)vrow0 * NSP + m0 + vch * 8;
#pragma unroll
      for (int i = 0; i < 8; ++i) kreg[i] = *(const bf16x8*)(kp + (size_t)i * 8 * CCH);
#pragma unroll
      for (int i = 0; i < 8; ++i) vreg[i] = *(const bf16x8*)(vp + (size_t)i * 32 * NSP);
    }
    // ---- S = Q K^T ----
    f32x4 s[4];
#pragma unroll
    for (int mb = 0; mb < 4; ++mb) s[mb] = (f32x4){0.f, 0.f, 0.f, 0.f};
#pragma unroll
    for (int kc = 0; kc < 8; ++kc) {
#pragma unroll
      for (int mb = 0; mb < 4; ++mb) {
        int row = mb * 16 + l16;
        bf16x8 bf = *(bf16x8*)(Ks + row * 256 + (((kc * 4 + quad) ^ (row & 7)) * 8));
        s[mb] = __builtin_amdgcn_mfma_f32_16x16x32_bf16(a_q[kc], bf, s[mb], 0, 0, 0);
      }
    }
    // ---- online softmax ----
    float mx[4], alpha[4], ls[4];
#pragma unroll
    for (int r = 0; r < 4; ++r)
      mx[r] = fmaxf(fmaxf(s[0][r], s[1][r]), fmaxf(s[2][r], s[3][r]));
#pragma unroll
    for (int off = 1; off < 16; off <<= 1)
#pragma unroll
      for (int r = 0; r < 4; ++r) mx[r] = fmaxf(mx[r], __shfl_xor(mx[r], off, 16));
#pragma unroll
    for (int r = 0; r < 4; ++r) {
      float mnew = fmaxf(m_run[r], mx[r]);
      alpha[r] = __expf(m_run[r] - mnew);
      m_run[r] = mnew;
      ls[r] = 0.f;
    }
#pragma unroll
    for (int mb = 0; mb < 4; ++mb)
#pragma unroll
      for (int r = 0; r < 4; ++r) {
        float p = __expf(s[mb][r] - m_run[r]);
        s[mb][r] = p;
        ls[r] += p;
      }
#pragma unroll
    for (int off = 1; off < 16; off <<= 1)
#pragma unroll
      for (int r = 0; r < 4; ++r) ls[r] += __shfl_xor(ls[r], off, 16);
    f32x4 alphav;
#pragma unroll
    for (int r = 0; r < 4; ++r) {
      l_run[r] = l_run[r] * alpha[r] + ls[r];
      alphav[r] = alpha[r];
    }
#pragma unroll
    for (int cb = 0; cb < 16; ++cb) accO[cb] *= alphav;
    // ---- P: C-layout -> bf16 A-layout via per-wave LDS ----
#pragma unroll
    for (int mb = 0; mb < 4; ++mb)
#pragma unroll
      for (int r = 0; r < 4; ++r) {
        int prow = quad * 4 + r;
        int pcol = mb * 16 + l16;
        Ps[(w * 16 + prow) * 64 + (((pcol >> 3) ^ (prow & 7)) * 8) + (pcol & 7)] =
            f2bf(s[mb][r]);
      }
    bf16x8 pa[2];
#pragma unroll
    for (int ks = 0; ks < 2; ++ks)
      pa[ks] = *(bf16x8*)(Ps + (w * 16 + l16) * 64 +
                          (((ks * 4 + quad) ^ (l16 & 7)) * 8));
    // ---- O += P V^T ----
#pragma unroll
    for (int cb = 0; cb < 16; ++cb) {
#pragma unroll
      for (int ks = 0; ks < 2; ++ks) {
        int vrow = cb * 16 + l16;
        bf16x8 bf = *(bf16x8*)(Vs + vrow * 64 + (((ks * 4 + quad) ^ (vrow & 7)) * 8));
        accO[cb] = __builtin_amdgcn_mfma_f32_16x16x32_bf16(pa[ks], bf, accO[cb], 0, 0, 0);
      }
    }
    __syncthreads();
    if (t < TILES_PER_HALF - 1) {
#pragma unroll
      for (int i = 0; i < 8; ++i) *(bf16x8*)(Ks + (krow0 + 8 * i) * 256 + koff) = kreg[i];
#pragma unroll
      for (int i = 0; i < 8; ++i) *(bf16x8*)(Vs + (vrow0 + 32 * i) * 64 + voff) = vreg[i];
      __syncthreads();
    }
  }
  // ---- epilogue: unnormalized partial O + stats ----
#pragma unroll
  for (int cb = 0; cb < 16; ++cb)
#pragma unroll
    for (int r = 0; r < 4; ++r)
      Fo[(cb * 16 + l16) * 68 + w * 16 + quad * 4 + r] = accO[cb][r];
  size_t sbase = ((size_t)kh * BB + b) * NSP + n0;
  if (l16 == 0) {
#pragma unroll
    for (int r = 0; r < 4; ++r) {
      pm[sbase + w * 16 + quad * 4 + r] = m_run[r];
      pl[sbase + w * 16 + quad * 4 + r] = l_run[r];
    }
  }
  __syncthreads();
  float* ob = po + (((size_t)kh * BB + b) * CCH) * NSP;
#pragma unroll
  for (int i = 0; i < 16; ++i) {
    int idx = tid + 256 * i;
    int c = idx >> 4, ng = (idx & 15) * 4;
    *(float4*)(ob + (size_t)c * NSP + n0 + ng) = *(float4*)&Fo[c * 68 + ng];
  }
}

// ---------------- merge the two key-halves -> h [b][c][n] fp32 ----------
__global__ __launch_bounds__(256) void merge_kernel(
    const float* __restrict__ po, const float* __restrict__ pm,
    const float* __restrict__ pl, float* __restrict__ h) {
  __shared__ float w0s[64], w1s[64];
  int b = blockIdx.x & 3;
  int n0 = (blockIdx.x >> 2) * 64;
  int tid = threadIdx.x;
  if (tid < 64) {
    size_t s0 = (size_t)b * NSP + n0 + tid;
    size_t s1 = ((size_t)BB + b) * NSP + n0 + tid;
    float m0 = pm[s0], m1 = pm[s1];
    float M = fmaxf(m0, m1);
    float a0 = __expf(m0 - M), a1 = __expf(m1 - M);
    float L = pl[s0] * a0 + pl[s1] * a1;
    float linv = 1.f / L;
    w0s[tid] = a0 * linv;
    w1s[tid] = a1 * linv;
  }
  __syncthreads();
  const float* p0 = po + (size_t)b * CCH * NSP;
  const float* p1 = po + ((size_t)BB + b) * CCH * NSP;
  float* hb = h + (size_t)b * CCH * NSP;
#pragma unroll
  for (int i = 0; i < 16; ++i) {
    int idx = tid + 256 * i;
    int c = idx >> 4, ng = (idx & 15) * 4;
    size_t off = (size_t)c * NSP + n0 + ng;
    float4 o0 = *(const float4*)(p0 + off);
    float4 o1 = *(const float4*)(p1 + off);
    float4 r;
    r.x = o0.x * w0s[ng] + o1.x * w1s[ng];
    r.y = o0.y * w0s[ng + 1] + o1.y * w1s[ng + 1];
    r.z = o0.z * w0s[ng + 2] + o1.z * w1s[ng + 2];
    r.w = o0.w * w0s[ng + 3] + o1.w * w1s[ng + 3];
    *(float4*)(hb + off) = r;
  }
}

// ---------------- proj + residual + /sqrt(2) ----------------
__global__ __launch_bounds__(256) void proj_kernel(
    const float* __restrict__ ho, const float* __restrict__ Wp,
    const float* __restrict__ bp, const float* __restrict__ x,
    float* __restrict__ out) {
  __shared__ __align__(16) float Ws[32][64];
  __shared__ __align__(16) float Hs[32][64];
  int n0 = blockIdx.x * 64;
  int d0 = blockIdx.y * 64;
  int b = blockIdx.z;
  const float* hb = ho + (size_t)b * CCH * NSP;
  int tid = threadIdx.x;
  int tx = tid & 15, ty = tid >> 4;
  int srow = tid >> 4, sc4 = tid & 15;
  float acc[4][4] = {};
  for (int c0 = 0; c0 < CCH; c0 += 32) {
#pragma unroll
    for (int i = 0; i < 2; ++i) {
      int row = srow + 16 * i;
      *(float4*)&Ws[row][sc4 * 4] =
          *(const float4*)&Wp[(size_t)(c0 + row) * CCH + d0 + sc4 * 4];
      *(float4*)&Hs[row][sc4 * 4] =
          *(const float4*)&hb[(size_t)(c0 + row) * NSP + n0 + sc4 * 4];
    }
    __syncthreads();
    for (int cc = 0; cc < 32; ++cc) {
      float4 w4 = *(const float4*)&Ws[cc][ty * 4];
      float4 h4 = *(const float4*)&Hs[cc][tx * 4];
      const float wr[4] = {w4.x, w4.y, w4.z, w4.w};
      const float hr[4] = {h4.x, h4.y, h4.z, h4.w};
#pragma unroll
      for (int i = 0; i < 4; ++i)
#pragma unroll
        for (int j = 0; j < 4; ++j) acc[i][j] += wr[i] * hr[j];
    }
    __syncthreads();
  }
#pragma unroll
  for (int i = 0; i < 4; ++i) {
    int d = d0 + ty * 4 + i;
    float bi = bp[d];
    size_t off = ((size_t)b * CCH + d) * NSP + n0 + tx * 4;
    float4 xr = *(const float4*)(x + off);
    float4 r;
    r.x = (acc[i][0] + bi + xr.x) * RSQRT2;
    r.y = (acc[i][1] + bi + xr.y) * RSQRT2;
    r.z = (acc[i][2] + bi + xr.z) * RSQRT2;
    r.w = (acc[i][3] + bi + xr.w) * RSQRT2;
    *(float4*)(out + off) = r;
  }
}

extern "C" void kernel_launch(void* const* d_in, const int* in_sizes, int n_in,
                              void* d_out, int out_size, void* d_ws, size_t ws_size,
                              hipStream_t stream) {
  const float* x  = (const float*)d_in[0];
  const float* gw = (const float*)d_in[1];
  const float* gb = (const float*)d_in[2];
  const float* Wq = (const float*)d_in[3];
  const float* bq = (const float*)d_in[4];
  const float* Wk = (const float*)d_in[5];
  const float* bk = (const float*)d_in[6];
  const float* Wv = (const float*)d_in[7];
  const float* bv = (const float*)d_in[8];
  const float* Wp = (const float*)d_in[9];
  const float* bp = (const float*)d_in[10];
  float* out = (float*)d_out;

  const size_t SZ = (size_t)BB * CCH * NSP;  // 4.19M elems
  float* h  = (float*)d_ws;                  // gn out; later merged attn out
  short* qb = (short*)(h + SZ);              // bf16 [b][n][c], pre-scaled
  short* kb = qb + SZ;                       // bf16 [b][n][c]
  short* vb = kb + SZ;                       // bf16 [b][c][n]
  float* po = (float*)(vb + SZ);             // fp32 [2][b][c][n] partials
  float* pm = po + KSPLIT * SZ;              // [2][b][n]
  float* pl = pm + (size_t)KSPLIT * BB * NSP;

  gn_kernel<<<dim3(BB * 32), dim3(256), 0, stream>>>(x, gw, gb, h);
  qkv_kernel<<<dim3(64, 4, 12), dim3(256), 0, stream>>>(
      h, Wq, bq, Wk, bk, Wv, bv, qb, kb, vb);
  attn_kernel<<<dim3(512), dim3(256), 0, stream>>>(qb, kb, vb, po, pm, pl);
  merge_kernel<<<dim3(256), dim3(256), 0, stream>>>(po, pm, pl, h);
  proj_kernel<<<dim3(64, 4, BB), dim3(256), 0, stream>>>(h, Wp, bp, x, out);
}

// Round 4
// 418.749 us; speedup vs baseline: 1.0302x; 1.0302x over previous
//
#include <hip/hip_runtime.h>
#include <math.h>

// AttnBlock: GroupNorm(32) -> q,k,v 1x1 -> spatial attention -> proj -> resid.
// Round 4: S^T-formulation flash attention. A=K, B=Q gives S^T whose C-layout
// (lane = query, regs = keys) IS the B-operand layout of mfma 16x16x16_bf16,
// so P feeds PV straight from registers (no Ps LDS, no transpose). LDS = 64KB
// exactly -> 2 blocks/CU (m132). Merge fused into proj.

#define BB 4
#define CCH 256
#define NSP 4096
#define EPSV 1e-5f
#define ATTN_SCALE 0.0625f  // 256^-0.5
#define RSQRT2 0.70710678118654752440f
#define KSPLIT 2
#define TILES_PER_HALF 32   // 4096 / 64 / KSPLIT

typedef __attribute__((ext_vector_type(8))) short bf16x8;
typedef __attribute__((ext_vector_type(4))) short bf16x4;
typedef __attribute__((ext_vector_type(4))) float f32x4;

__device__ __forceinline__ short f2bf(float f) {
  union { float f; unsigned u; } a; a.f = f;
  unsigned r = a.u + 0x7fffu + ((a.u >> 16) & 1u);  // RTN-even
  return (short)(r >> 16);
}

__device__ __forceinline__ f32x4 mfma16x16x16(bf16x4 a, bf16x4 b, f32x4 c) {
#if __has_builtin(__builtin_amdgcn_mfma_f32_16x16x16bf16_1k)
  return __builtin_amdgcn_mfma_f32_16x16x16bf16_1k(a, b, c, 0, 0, 0);
#else
  asm volatile("v_mfma_f32_16x16x16_bf16 %0, %1, %2, %0"
               : "+v"(c) : "v"(a), "v"(b));
  return c;
#endif
}

// ---------------- GroupNorm ----------------
__global__ __launch_bounds__(256) void gn_kernel(
    const float* __restrict__ x, const float* __restrict__ gw,
    const float* __restrict__ gb, float* __restrict__ h) {
  int b = blockIdx.x >> 5;
  int g = blockIdx.x & 31;
  size_t base = ((size_t)b * CCH + (size_t)g * 8) * NSP;
  const float4* xv = (const float4*)(x + base);
  int tid = threadIdx.x;
  float s = 0.f, ss = 0.f;
  for (int i = tid; i < 8192; i += 256) {
    float4 v = xv[i];
    s += (v.x + v.y) + (v.z + v.w);
    ss += (v.x * v.x + v.y * v.y) + (v.z * v.z + v.w * v.w);
  }
#pragma unroll
  for (int off = 32; off > 0; off >>= 1) {
    s += __shfl_down(s, off, 64);
    ss += __shfl_down(ss, off, 64);
  }
  __shared__ float rs[4], rss[4], stat[2];
  int wv = tid >> 6;
  if ((tid & 63) == 0) { rs[wv] = s; rss[wv] = ss; }
  __syncthreads();
  if (tid == 0) {
    float S = rs[0] + rs[1] + rs[2] + rs[3];
    float SS = rss[0] + rss[1] + rss[2] + rss[3];
    float mean = S * (1.f / 32768.f);
    float var = SS * (1.f / 32768.f) - mean * mean;
    stat[0] = mean;
    stat[1] = rsqrtf(var + EPSV);
  }
  __syncthreads();
  float mean = stat[0], rstd = stat[1];
  float4* hv = (float4*)(h + base);
  for (int i = tid; i < 8192; i += 256) {
    int c = g * 8 + (i >> 10);
    float a = gw[c] * rstd;
    float bb = gb[c] - mean * a;
    float4 v = xv[i];
    float4 o;
    o.x = v.x * a + bb; o.y = v.y * a + bb;
    o.z = v.z * a + bb; o.w = v.w * a + bb;
    hv[i] = o;
  }
}

// ---------------- QKV: fp32 GEMM, bf16 outputs in MFMA-friendly layouts ----
__global__ __launch_bounds__(256) void qkv_kernel(
    const float* __restrict__ h,
    const float* __restrict__ Wq, const float* __restrict__ bq,
    const float* __restrict__ Wk, const float* __restrict__ bk,
    const float* __restrict__ Wv, const float* __restrict__ bv,
    short* __restrict__ qo, short* __restrict__ ko, short* __restrict__ vo) {
  __shared__ __align__(16) float Ws[32][64];
  __shared__ __align__(16) float Hs[32][64];
  __shared__ __align__(16) float Ts[64][68];
  int n0 = blockIdx.x * 64;
  int d0 = blockIdx.y * 64;
  int b = blockIdx.z & 3;
  int op = blockIdx.z >> 2;
  const float* W = (op == 0) ? Wq : (op == 1) ? Wk : Wv;
  const float* bias = (op == 0) ? bq : (op == 1) ? bk : bv;
  const float* hb = h + (size_t)b * CCH * NSP;
  int tid = threadIdx.x;
  int tx = tid & 15, ty = tid >> 4;
  int srow = tid >> 4, sc4 = tid & 15;
  float acc[4][4] = {};
  for (int c0 = 0; c0 < CCH; c0 += 32) {
#pragma unroll
    for (int i = 0; i < 2; ++i) {
      int row = srow + 16 * i;
      *(float4*)&Ws[row][sc4 * 4] =
          *(const float4*)&W[(size_t)(c0 + row) * CCH + d0 + sc4 * 4];
      *(float4*)&Hs[row][sc4 * 4] =
          *(const float4*)&hb[(size_t)(c0 + row) * NSP + n0 + sc4 * 4];
    }
    __syncthreads();
    for (int cc = 0; cc < 32; ++cc) {
      float4 w4 = *(const float4*)&Ws[cc][ty * 4];
      float4 h4 = *(const float4*)&Hs[cc][tx * 4];
      const float wr[4] = {w4.x, w4.y, w4.z, w4.w};
      const float hr[4] = {h4.x, h4.y, h4.z, h4.w};
#pragma unroll
      for (int i = 0; i < 4; ++i)
#pragma unroll
        for (int j = 0; j < 4; ++j) acc[i][j] += wr[i] * hr[j];
    }
    __syncthreads();
  }
  if (op == 2) {  // v: [c][n] bf16
    short* ob = vo + (size_t)b * CCH * NSP;
#pragma unroll
    for (int i = 0; i < 4; ++i) {
      int d = d0 + ty * 4 + i;
      float bi = bias[d];
      bf16x4 r;
      r[0] = f2bf(acc[i][0] + bi); r[1] = f2bf(acc[i][1] + bi);
      r[2] = f2bf(acc[i][2] + bi); r[3] = f2bf(acc[i][3] + bi);
      *(bf16x4*)(ob + (size_t)d * NSP + n0 + tx * 4) = r;
    }
  } else {  // q/k: transpose to [n][c] bf16 (q pre-scaled)
    float sc = (op == 0) ? ATTN_SCALE : 1.f;
#pragma unroll
    for (int i = 0; i < 4; ++i) {
      int d = d0 + ty * 4 + i;
      float bi = bias[d];
#pragma unroll
      for (int j = 0; j < 4; ++j) Ts[tx * 4 + j][ty * 4 + i] = (acc[i][j] + bi) * sc;
    }
    __syncthreads();
    short* ob = ((op == 0) ? qo : ko) + (size_t)b * NSP * CCH;
#pragma unroll
    for (int it = 0; it < 2; ++it) {
      int idx = tid + 256 * it;
      int row = idx >> 3, c8 = (idx & 7) * 8;
      float4 f0 = *(float4*)&Ts[row][c8];
      float4 f1 = *(float4*)&Ts[row][c8 + 4];
      bf16x8 r;
      r[0] = f2bf(f0.x); r[1] = f2bf(f0.y); r[2] = f2bf(f0.z); r[3] = f2bf(f0.w);
      r[4] = f2bf(f1.x); r[5] = f2bf(f1.y); r[6] = f2bf(f1.z); r[7] = f2bf(f1.w);
      *(bf16x8*)(ob + (size_t)(n0 + row) * CCH + d0 + c8) = r;
    }
  }
}

// ---------------- flash attention, S^T formulation, key-split partials ------
// q,k: [b][n][c] bf16 (q pre-scaled); v: [b][c][n] bf16.
// Writes unnormalized partial O [kh][b][c][n] fp32 + m,l stats [kh][b][n].
__global__ __launch_bounds__(256) void attn_kernel(
    const short* __restrict__ q, const short* __restrict__ k,
    const short* __restrict__ v, float* __restrict__ po,
    float* __restrict__ pm, float* __restrict__ pl) {
  __shared__ __align__(16) unsigned char smem[65536];   // exactly 64 KB
  short* Ks = (short*)smem;            // [64 m][256 c] swizzled (also Q stage)
  short* Vs = (short*)(smem + 32768);  // [256 c][64 m] swizzled
  float* Fo = (float*)smem;            // epilogue [128][68] fp32, two passes

  int bx = blockIdx.x;
  int b = bx & 3;
  int n0 = ((bx >> 2) & 63) << 6;
  int kh = bx >> 8;
  const short* qb = q + (size_t)b * NSP * CCH;
  const short* kb = k + (size_t)b * NSP * CCH;
  const short* vb = v + (size_t)b * CCH * NSP;
  int tid = threadIdx.x;
  int w = tid >> 6, lane = tid & 63, quad = lane >> 4, l16 = lane & 15;

  int krow0 = tid >> 5, kch = tid & 31;   // K/Q staging: rows krow0+8i
  int vrow0 = tid >> 3, vch = tid & 7;    // V staging: rows vrow0+32i
  int koff = (kch ^ (krow0 & 7)) * 8;
  int voff = (vch ^ (vrow0 & 7)) * 8;

  int mbase = kh * TILES_PER_HALF * 64;
  // ---- issue K0/V0 global loads, stage Q into Ks region, extract frags ----
  bf16x8 kreg[8], vreg[8];
  {
    const short* kp = kb + (size_t)(mbase + krow0) * CCH + kch * 8;
    const short* vp = vb + (size_t)vrow0 * NSP + mbase + vch * 8;
#pragma unroll
    for (int i = 0; i < 8; ++i) kreg[i] = *(const bf16x8*)(kp + (size_t)i * 8 * CCH);
#pragma unroll
    for (int i = 0; i < 8; ++i) vreg[i] = *(const bf16x8*)(vp + (size_t)i * 32 * NSP);
    const short* qp = qb + (size_t)(n0 + krow0) * CCH + kch * 8;
#pragma unroll
    for (int i = 0; i < 8; ++i) {
      bf16x8 t = *(const bf16x8*)(qp + (size_t)i * 8 * CCH);
      *(bf16x8*)(Ks + (krow0 + 8 * i) * 256 + koff) = t;
    }
  }
  __syncthreads();
  bf16x8 a_q[8];  // B-operand frag: lane l16 = query w*16+l16, k chunks = ch
  {
    int row = w * 16 + l16;
#pragma unroll
    for (int kc = 0; kc < 8; ++kc)
      a_q[kc] = *(bf16x8*)(Ks + row * 256 + (((kc * 4 + quad) ^ (row & 7)) * 8));
  }
  __syncthreads();  // all waves done reading Q from Ks region
#pragma unroll
  for (int i = 0; i < 8; ++i) *(bf16x8*)(Ks + (krow0 + 8 * i) * 256 + koff) = kreg[i];
#pragma unroll
  for (int i = 0; i < 8; ++i) *(bf16x8*)(Vs + (vrow0 + 32 * i) * 64 + voff) = vreg[i];
  __syncthreads();

  f32x4 accO[16];  // O^T C-layout: ch = cb*16 + quad*4 + r, query = l16
#pragma unroll
  for (int cb = 0; cb < 16; ++cb) accO[cb] = (f32x4){0.f, 0.f, 0.f, 0.f};
  float m_run = -1e30f, l_run = 0.f;  // per-lane: query w*16+l16

#pragma unroll 1
  for (int t = 0; t < TILES_PER_HALF; ++t) {
    if (t < TILES_PER_HALF - 1) {
      int m0 = mbase + (t + 1) * 64;
      const short* kp = kb + (size_t)(m0 + krow0) * CCH + kch * 8;
      const short* vp = vb + (size_t)vrow0 * NSP + m0 + vch * 8;
#pragma unroll
      for (int i = 0; i < 8; ++i) kreg[i] = *(const bf16x8*)(kp + (size_t)i * 8 * CCH);
#pragma unroll
      for (int i = 0; i < 8; ++i) vreg[i] = *(const bf16x8*)(vp + (size_t)i * 32 * NSP);
    }
    // ---- S^T = K Q^T : rows = keys (mb*16+quad*4+r), cols = queries (l16) --
    f32x4 s[4];
#pragma unroll
    for (int mb = 0; mb < 4; ++mb) s[mb] = (f32x4){0.f, 0.f, 0.f, 0.f};
#pragma unroll
    for (int kc = 0; kc < 8; ++kc) {
#pragma unroll
      for (int mb = 0; mb < 4; ++mb) {
        int row = mb * 16 + l16;
        bf16x8 kf = *(bf16x8*)(Ks + row * 256 + (((kc * 4 + quad) ^ (row & 7)) * 8));
        s[mb] = __builtin_amdgcn_mfma_f32_16x16x32_bf16(kf, a_q[kc], s[mb], 0, 0, 0);
      }
    }
    // ---- online softmax: per-lane scalar stats (one query per lane) ----
    float mx = -1e30f;
#pragma unroll
    for (int mb = 0; mb < 4; ++mb)
#pragma unroll
      for (int r = 0; r < 4; ++r) mx = fmaxf(mx, s[mb][r]);
    mx = fmaxf(mx, __shfl_xor(mx, 16));
    mx = fmaxf(mx, __shfl_xor(mx, 32));
    float mnew = fmaxf(m_run, mx);
    float alpha = __expf(m_run - mnew);
    m_run = mnew;
    float ls = 0.f;
    bf16x4 pb[4];
#pragma unroll
    for (int mb = 0; mb < 4; ++mb)
#pragma unroll
      for (int r = 0; r < 4; ++r) {
        float p = __expf(s[mb][r] - mnew);
        ls += p;
        pb[mb][r] = f2bf(p);
      }
    ls += __shfl_xor(ls, 16);
    ls += __shfl_xor(ls, 32);
    l_run = l_run * alpha + ls;
#pragma unroll
    for (int cb = 0; cb < 16; ++cb) accO[cb] *= alpha;
    // ---- O^T += V P^T : A = V-frag (b64 reads), B = pb straight from regs --
#pragma unroll
    for (int kw = 0; kw < 4; ++kw) {
#pragma unroll
      for (int cb = 0; cb < 16; ++cb) {
        int row = cb * 16 + l16;
        int chunk = (kw * 2 + (quad >> 1)) ^ (row & 7);
        bf16x4 vf = *(bf16x4*)(Vs + row * 64 + chunk * 8 + (quad & 1) * 4);
        accO[cb] = mfma16x16x16(vf, pb[kw], accO[cb]);
      }
    }
    __syncthreads();
    if (t < TILES_PER_HALF - 1) {
#pragma unroll
      for (int i = 0; i < 8; ++i) *(bf16x8*)(Ks + (krow0 + 8 * i) * 256 + koff) = kreg[i];
#pragma unroll
      for (int i = 0; i < 8; ++i) *(bf16x8*)(Vs + (vrow0 + 32 * i) * 64 + voff) = vreg[i];
      __syncthreads();
    }
  }
  // ---- stats ----
  size_t sbase = ((size_t)kh * BB + b) * NSP + n0;
  if (quad == 0) {
    pm[sbase + w * 16 + l16] = m_run;
    pl[sbase + w * 16 + l16] = l_run;
  }
  // ---- epilogue: unnormalized partial O, 2 passes of 128 channels ----
  float* ob = po + ((size_t)kh * BB + b) * CCH * NSP;
#pragma unroll
  for (int p = 0; p < 2; ++p) {
    __syncthreads();
#pragma unroll
    for (int cb = 0; cb < 8; ++cb)
#pragma unroll
      for (int r = 0; r < 4; ++r)
        Fo[(cb * 16 + quad * 4 + r) * 68 + w * 16 + l16] = accO[p * 8 + cb][r];
    __syncthreads();
#pragma unroll
    for (int i = 0; i < 8; ++i) {
      int idx = tid + 256 * i;
      int c = idx >> 4, ng = (idx & 15) * 4;
      *(float4*)(ob + (size_t)(p * 128 + c) * NSP + n0 + ng) = *(float4*)&Fo[c * 68 + ng];
    }
  }
}

// ---------------- proj (+fused merge) + residual + /sqrt(2) ----------------
__global__ __launch_bounds__(256) void proj_kernel(
    const float* __restrict__ po, const float* __restrict__ pm,
    const float* __restrict__ pl, const float* __restrict__ Wp,
    const float* __restrict__ bp, const float* __restrict__ x,
    float* __restrict__ out) {
  __shared__ __align__(16) float Ws[32][64];
  __shared__ __align__(16) float Hs[32][64];
  __shared__ float w0s[64], w1s[64];
  int n0 = blockIdx.x * 64;
  int d0 = blockIdx.y * 64;
  int b = blockIdx.z;
  int tid = threadIdx.x;
  if (tid < 64) {
    size_t s0 = (size_t)b * NSP + n0 + tid;
    size_t s1 = ((size_t)BB + b) * NSP + n0 + tid;
    float m0 = pm[s0], m1 = pm[s1];
    float M = fmaxf(m0, m1);
    float a0 = __expf(m0 - M), a1 = __expf(m1 - M);
    float L = pl[s0] * a0 + pl[s1] * a1;
    float linv = 1.f / L;
    w0s[tid] = a0 * linv;
    w1s[tid] = a1 * linv;
  }
  const float* p0 = po + (size_t)b * CCH * NSP;
  const float* p1 = po + ((size_t)BB + b) * CCH * NSP;
  int tx = tid & 15, ty = tid >> 4;
  int srow = tid >> 4, sc4 = tid & 15;
  float acc[4][4] = {};
  __syncthreads();
  float4 w0v = *(float4*)&w0s[sc4 * 4];
  float4 w1v = *(float4*)&w1s[sc4 * 4];
  for (int c0 = 0; c0 < CCH; c0 += 32) {
#pragma unroll
    for (int i = 0; i < 2; ++i) {
      int row = srow + 16 * i;
      *(float4*)&Ws[row][sc4 * 4] =
          *(const float4*)&Wp[(size_t)(c0 + row) * CCH + d0 + sc4 * 4];
      size_t off = (size_t)(c0 + row) * NSP + n0 + sc4 * 4;
      float4 h0 = *(const float4*)(p0 + off);
      float4 h1 = *(const float4*)(p1 + off);
      float4 hm;
      hm.x = h0.x * w0v.x + h1.x * w1v.x;
      hm.y = h0.y * w0v.y + h1.y * w1v.y;
      hm.z = h0.z * w0v.z + h1.z * w1v.z;
      hm.w = h0.w * w0v.w + h1.w * w1v.w;
      *(float4*)&Hs[row][sc4 * 4] = hm;
    }
    __syncthreads();
    for (int cc = 0; cc < 32; ++cc) {
      float4 w4 = *(const float4*)&Ws[cc][ty * 4];
      float4 h4 = *(const float4*)&Hs[cc][tx * 4];
      const float wr[4] = {w4.x, w4.y, w4.z, w4.w};
      const float hr[4] = {h4.x, h4.y, h4.z, h4.w};
#pragma unroll
      for (int i = 0; i < 4; ++i)
#pragma unroll
        for (int j = 0; j < 4; ++j) acc[i][j] += wr[i] * hr[j];
    }
    __syncthreads();
  }
#pragma unroll
  for (int i = 0; i < 4; ++i) {
    int d = d0 + ty * 4 + i;
    float bi = bp[d];
    size_t off = ((size_t)b * CCH + d) * NSP + n0 + tx * 4;
    float4 xr = *(const float4*)(x + off);
    float4 r;
    r.x = (acc[i][0] + bi + xr.x) * RSQRT2;
    r.y = (acc[i][1] + bi + xr.y) * RSQRT2;
    r.z = (acc[i][2] + bi + xr.z) * RSQRT2;
    r.w = (acc[i][3] + bi + xr.w) * RSQRT2;
    *(float4*)(out + off) = r;
  }
}

extern "C" void kernel_launch(void* const* d_in, const int* in_sizes, int n_in,
                              void* d_out, int out_size, void* d_ws, size_t ws_size,
                              hipStream_t stream) {
  const float* x  = (const float*)d_in[0];
  const float* gw = (const float*)d_in[1];
  const float* gb = (const float*)d_in[2];
  const float* Wq = (const float*)d_in[3];
  const float* bq = (const float*)d_in[4];
  const float* Wk = (const float*)d_in[5];
  const float* bk = (const float*)d_in[6];
  const float* Wv = (const float*)d_in[7];
  const float* bv = (const float*)d_in[8];
  const float* Wp = (const float*)d_in[9];
  const float* bp = (const float*)d_in[10];
  float* out = (float*)d_out;

  const size_t SZ = (size_t)BB * CCH * NSP;  // 4.19M elems
  float* h  = (float*)d_ws;                  // gn out (qkv input)
  short* qb = (short*)(h + SZ);              // bf16 [b][n][c], pre-scaled
  short* kb = qb + SZ;                       // bf16 [b][n][c]
  short* vb = kb + SZ;                       // bf16 [b][c][n]
  float* po = (float*)(vb + SZ);             // fp32 [2][b][c][n] partials
  float* pm = po + KSPLIT * SZ;              // [2][b][n]
  float* pl = pm + (size_t)KSPLIT * BB * NSP;

  gn_kernel<<<dim3(BB * 32), dim3(256), 0, stream>>>(x, gw, gb, h);
  qkv_kernel<<<dim3(64, 4, 12), dim3(256), 0, stream>>>(
      h, Wq, bq, Wk, bk, Wv, bv, qb, kb, vb);
  attn_kernel<<<dim3(512), dim3(256), 0, stream>>>(qb, kb, vb, po, pm, pl);
  proj_kernel<<<dim3(64, 4, BB), dim3(256), 0, stream>>>(po, pm, pl, Wp, bp, x, out);
}

// Round 5
// 344.999 us; speedup vs baseline: 1.2505x; 1.2138x over previous
//
#include <hip/hip_runtime.h>
#include <math.h>

// AttnBlock: GroupNorm(32) -> q,k,v 1x1 -> spatial attention -> proj -> resid.
// Round 5: 8-wave (512-thread) attention blocks, 128 queries/block. Occupancy
// is built into the workgroup (2 waves/SIMD) instead of relying on the
// dispatcher to co-schedule 64KB-LDS blocks (rounds 3/4 proved it won't).
// S^T formulation: P feeds PV straight from registers (no P LDS round-trip).

#define BB 4
#define CCH 256
#define NSP 4096
#define EPSV 1e-5f
#define ATTN_SCALE 0.0625f  // 256^-0.5
#define RSQRT2 0.70710678118654752440f
#define KSPLIT 2
#define TILES_PER_HALF 32   // 4096 / 64 / KSPLIT

typedef __attribute__((ext_vector_type(8))) short bf16x8;
typedef __attribute__((ext_vector_type(4))) short bf16x4;
typedef __attribute__((ext_vector_type(4))) float f32x4;

__device__ __forceinline__ short f2bf(float f) {
  union { float f; unsigned u; } a; a.f = f;
  unsigned r = a.u + 0x7fffu + ((a.u >> 16) & 1u);  // RTN-even
  return (short)(r >> 16);
}

__device__ __forceinline__ f32x4 mfma16x16x16(bf16x4 a, bf16x4 b, f32x4 c) {
#if __has_builtin(__builtin_amdgcn_mfma_f32_16x16x16bf16_1k)
  return __builtin_amdgcn_mfma_f32_16x16x16bf16_1k(a, b, c, 0, 0, 0);
#else
  asm volatile("v_mfma_f32_16x16x16_bf16 %0, %1, %2, %0"
               : "+v"(c) : "v"(a), "v"(b));
  return c;
#endif
}

// ---------------- GroupNorm ----------------
__global__ __launch_bounds__(256) void gn_kernel(
    const float* __restrict__ x, const float* __restrict__ gw,
    const float* __restrict__ gb, float* __restrict__ h) {
  int b = blockIdx.x >> 5;
  int g = blockIdx.x & 31;
  size_t base = ((size_t)b * CCH + (size_t)g * 8) * NSP;
  const float4* xv = (const float4*)(x + base);
  int tid = threadIdx.x;
  float s = 0.f, ss = 0.f;
  for (int i = tid; i < 8192; i += 256) {
    float4 v = xv[i];
    s += (v.x + v.y) + (v.z + v.w);
    ss += (v.x * v.x + v.y * v.y) + (v.z * v.z + v.w * v.w);
  }
#pragma unroll
  for (int off = 32; off > 0; off >>= 1) {
    s += __shfl_down(s, off, 64);
    ss += __shfl_down(ss, off, 64);
  }
  __shared__ float rs[4], rss[4], stat[2];
  int wv = tid >> 6;
  if ((tid & 63) == 0) { rs[wv] = s; rss[wv] = ss; }
  __syncthreads();
  if (tid == 0) {
    float S = rs[0] + rs[1] + rs[2] + rs[3];
    float SS = rss[0] + rss[1] + rss[2] + rss[3];
    float mean = S * (1.f / 32768.f);
    float var = SS * (1.f / 32768.f) - mean * mean;
    stat[0] = mean;
    stat[1] = rsqrtf(var + EPSV);
  }
  __syncthreads();
  float mean = stat[0], rstd = stat[1];
  float4* hv = (float4*)(h + base);
  for (int i = tid; i < 8192; i += 256) {
    int c = g * 8 + (i >> 10);
    float a = gw[c] * rstd;
    float bb = gb[c] - mean * a;
    float4 v = xv[i];
    float4 o;
    o.x = v.x * a + bb; o.y = v.y * a + bb;
    o.z = v.z * a + bb; o.w = v.w * a + bb;
    hv[i] = o;
  }
}

// ---------------- QKV: fp32 GEMM, bf16 outputs in MFMA-friendly layouts ----
__global__ __launch_bounds__(256) void qkv_kernel(
    const float* __restrict__ h,
    const float* __restrict__ Wq, const float* __restrict__ bq,
    const float* __restrict__ Wk, const float* __restrict__ bk,
    const float* __restrict__ Wv, const float* __restrict__ bv,
    short* __restrict__ qo, short* __restrict__ ko, short* __restrict__ vo) {
  __shared__ __align__(16) float Ws[32][64];
  __shared__ __align__(16) float Hs[32][64];
  __shared__ __align__(16) float Ts[64][68];
  int n0 = blockIdx.x * 64;
  int d0 = blockIdx.y * 64;
  int b = blockIdx.z & 3;
  int op = blockIdx.z >> 2;
  const float* W = (op == 0) ? Wq : (op == 1) ? Wk : Wv;
  const float* bias = (op == 0) ? bq : (op == 1) ? bk : bv;
  const float* hb = h + (size_t)b * CCH * NSP;
  int tid = threadIdx.x;
  int tx = tid & 15, ty = tid >> 4;
  int srow = tid >> 4, sc4 = tid & 15;
  float acc[4][4] = {};
  for (int c0 = 0; c0 < CCH; c0 += 32) {
#pragma unroll
    for (int i = 0; i < 2; ++i) {
      int row = srow + 16 * i;
      *(float4*)&Ws[row][sc4 * 4] =
          *(const float4*)&W[(size_t)(c0 + row) * CCH + d0 + sc4 * 4];
      *(float4*)&Hs[row][sc4 * 4] =
          *(const float4*)&hb[(size_t)(c0 + row) * NSP + n0 + sc4 * 4];
    }
    __syncthreads();
    for (int cc = 0; cc < 32; ++cc) {
      float4 w4 = *(const float4*)&Ws[cc][ty * 4];
      float4 h4 = *(const float4*)&Hs[cc][tx * 4];
      const float wr[4] = {w4.x, w4.y, w4.z, w4.w};
      const float hr[4] = {h4.x, h4.y, h4.z, h4.w};
#pragma unroll
      for (int i = 0; i < 4; ++i)
#pragma unroll
        for (int j = 0; j < 4; ++j) acc[i][j] += wr[i] * hr[j];
    }
    __syncthreads();
  }
  if (op == 2) {  // v: [c][n] bf16
    short* ob = vo + (size_t)b * CCH * NSP;
#pragma unroll
    for (int i = 0; i < 4; ++i) {
      int d = d0 + ty * 4 + i;
      float bi = bias[d];
      bf16x4 r;
      r[0] = f2bf(acc[i][0] + bi); r[1] = f2bf(acc[i][1] + bi);
      r[2] = f2bf(acc[i][2] + bi); r[3] = f2bf(acc[i][3] + bi);
      *(bf16x4*)(ob + (size_t)d * NSP + n0 + tx * 4) = r;
    }
  } else {  // q/k: transpose to [n][c] bf16 (q pre-scaled)
    float sc = (op == 0) ? ATTN_SCALE : 1.f;
#pragma unroll
    for (int i = 0; i < 4; ++i) {
      int d = d0 + ty * 4 + i;
      float bi = bias[d];
#pragma unroll
      for (int j = 0; j < 4; ++j) Ts[tx * 4 + j][ty * 4 + i] = (acc[i][j] + bi) * sc;
    }
    __syncthreads();
    short* ob = ((op == 0) ? qo : ko) + (size_t)b * NSP * CCH;
#pragma unroll
    for (int it = 0; it < 2; ++it) {
      int idx = tid + 256 * it;
      int row = idx >> 3, c8 = (idx & 7) * 8;
      float4 f0 = *(float4*)&Ts[row][c8];
      float4 f1 = *(float4*)&Ts[row][c8 + 4];
      bf16x8 r;
      r[0] = f2bf(f0.x); r[1] = f2bf(f0.y); r[2] = f2bf(f0.z); r[3] = f2bf(f0.w);
      r[4] = f2bf(f1.x); r[5] = f2bf(f1.y); r[6] = f2bf(f1.z); r[7] = f2bf(f1.w);
      *(bf16x8*)(ob + (size_t)(n0 + row) * CCH + d0 + c8) = r;
    }
  }
}

// ---------------- flash attention: 8 waves, 128 queries/block --------------
// q,k: [b][n][c] bf16 (q pre-scaled); v: [b][c][n] bf16.
// Writes unnormalized partial O [kh][b][c][n] fp32 + m,l stats [kh][b][n].
__global__ __launch_bounds__(512, 2) void attn_kernel(
    const short* __restrict__ q, const short* __restrict__ k,
    const short* __restrict__ v, float* __restrict__ po,
    float* __restrict__ pm, float* __restrict__ pl) {
  __shared__ __align__(16) unsigned char smem[65536];   // exactly 64 KB
  short* Ks = (short*)smem;            // [64 m][256 c] swizzled (also Q stage)
  short* Vs = (short*)(smem + 32768);  // [256 c][64 m] swizzled

  int bx = blockIdx.x;
  int b = bx & 3;
  int n0 = ((bx >> 2) & 31) << 7;   // 128-query block
  int kh = bx >> 7;                 // key half
  const short* qb = q + (size_t)b * NSP * CCH;
  const short* kb = k + (size_t)b * NSP * CCH;
  const short* vb = v + (size_t)b * CCH * NSP;
  int tid = threadIdx.x;
  int w = tid >> 6, lane = tid & 63, quad = lane >> 4, l16 = lane & 15;

  // staging geometry (512 threads)
  int krow0 = tid >> 5, kch = tid & 31;   // K rows krow0+16i, i<4
  int vrow0 = tid >> 3, vch = tid & 7;    // V rows vrow0+64i, i<4
  int koff = (kch ^ (krow0 & 7)) * 8;     // row&7 invariant under +16i
  int voff = (vch ^ (vrow0 & 7)) * 8;     // row&7 invariant under +64i
  int qrow = tid >> 3, qch = tid & 7;     // Q: row qrow, chunks qch+8i

  int mbase = kh * TILES_PER_HALF * 64;
  // ---- prefetch K0/V0 while staging Q ----
  bf16x8 kreg[4], vreg[4];
  {
    const short* kp = kb + (size_t)(mbase + krow0) * CCH + kch * 8;
    const short* vp = vb + (size_t)vrow0 * NSP + mbase + vch * 8;
#pragma unroll
    for (int i = 0; i < 4; ++i) kreg[i] = *(const bf16x8*)(kp + (size_t)i * 16 * CCH);
#pragma unroll
    for (int i = 0; i < 4; ++i) vreg[i] = *(const bf16x8*)(vp + (size_t)i * 64 * NSP);
  }
  // ---- stage Q in two 64-row passes through Ks region, extract B-frags ----
  bf16x8 a_q[8];
#pragma unroll
  for (int p = 0; p < 2; ++p) {
    const short* qp = qb + (size_t)(n0 + p * 64 + qrow) * CCH;
#pragma unroll
    for (int i = 0; i < 4; ++i) {
      int chunk = qch + 8 * i;
      bf16x8 t = *(const bf16x8*)(qp + chunk * 8);
      *(bf16x8*)(Ks + qrow * 256 + ((chunk ^ (qrow & 7)) * 8)) = t;
    }
    __syncthreads();
    if ((w >> 2) == p) {
      int row = (w & 3) * 16 + l16;
#pragma unroll
      for (int kc = 0; kc < 8; ++kc)
        a_q[kc] = *(bf16x8*)(Ks + row * 256 + (((kc * 4 + quad) ^ (row & 7)) * 8));
    }
    __syncthreads();
  }
  // ---- commit K0/V0 to LDS ----
#pragma unroll
  for (int i = 0; i < 4; ++i) *(bf16x8*)(Ks + (krow0 + 16 * i) * 256 + koff) = kreg[i];
#pragma unroll
  for (int i = 0; i < 4; ++i) *(bf16x8*)(Vs + (vrow0 + 64 * i) * 64 + voff) = vreg[i];
  __syncthreads();

  f32x4 accO[16];  // O^T C-layout: ch = cb*16 + quad*4 + r, query = w*16+l16
#pragma unroll
  for (int cb = 0; cb < 16; ++cb) accO[cb] = (f32x4){0.f, 0.f, 0.f, 0.f};
  float m_run = -1e30f, l_run = 0.f;

#pragma unroll 1
  for (int t = 0; t < TILES_PER_HALF; ++t) {
    if (t < TILES_PER_HALF - 1) {
      int m0 = mbase + (t + 1) * 64;
      const short* kp = kb + (size_t)(m0 + krow0) * CCH + kch * 8;
      const short* vp = vb + (size_t)vrow0 * NSP + m0 + vch * 8;
#pragma unroll
      for (int i = 0; i < 4; ++i) kreg[i] = *(const bf16x8*)(kp + (size_t)i * 16 * CCH);
#pragma unroll
      for (int i = 0; i < 4; ++i) vreg[i] = *(const bf16x8*)(vp + (size_t)i * 64 * NSP);
    }
    // ---- S^T = K Q^T : rows = keys, cols = this wave's 16 queries ----
    f32x4 s[4];
#pragma unroll
    for (int mb = 0; mb < 4; ++mb) s[mb] = (f32x4){0.f, 0.f, 0.f, 0.f};
#pragma unroll
    for (int kc = 0; kc < 8; ++kc) {
#pragma unroll
      for (int mb = 0; mb < 4; ++mb) {
        int row = mb * 16 + l16;
        bf16x8 kf = *(bf16x8*)(Ks + row * 256 + (((kc * 4 + quad) ^ (row & 7)) * 8));
        s[mb] = __builtin_amdgcn_mfma_f32_16x16x32_bf16(kf, a_q[kc], s[mb], 0, 0, 0);
      }
    }
    // ---- online softmax: per-lane scalar stats (one query per lane) ----
    float mx = -1e30f;
#pragma unroll
    for (int mb = 0; mb < 4; ++mb)
#pragma unroll
      for (int r = 0; r < 4; ++r) mx = fmaxf(mx, s[mb][r]);
    mx = fmaxf(mx, __shfl_xor(mx, 16));
    mx = fmaxf(mx, __shfl_xor(mx, 32));
    float mnew = fmaxf(m_run, mx);
    float alpha = __expf(m_run - mnew);
    m_run = mnew;
    float ls = 0.f;
    bf16x4 pb[4];
#pragma unroll
    for (int mb = 0; mb < 4; ++mb)
#pragma unroll
      for (int r = 0; r < 4; ++r) {
        float p = __expf(s[mb][r] - mnew);
        ls += p;
        pb[mb][r] = f2bf(p);
      }
    ls += __shfl_xor(ls, 16);
    ls += __shfl_xor(ls, 32);
    l_run = l_run * alpha + ls;
#pragma unroll
    for (int cb = 0; cb < 16; ++cb) accO[cb] *= alpha;
    // ---- O^T += V P^T : A = V-frag (b64), B = pb from registers ----
#pragma unroll
    for (int kw = 0; kw < 4; ++kw) {
#pragma unroll
      for (int cb = 0; cb < 16; ++cb) {
        int row = cb * 16 + l16;
        int chunk = (kw * 2 + (quad >> 1)) ^ (row & 7);
        bf16x4 vf = *(bf16x4*)(Vs + row * 64 + chunk * 8 + (quad & 1) * 4);
        accO[cb] = mfma16x16x16(vf, pb[kw], accO[cb]);
      }
    }
    __syncthreads();
    if (t < TILES_PER_HALF - 1) {
#pragma unroll
      for (int i = 0; i < 4; ++i) *(bf16x8*)(Ks + (krow0 + 16 * i) * 256 + koff) = kreg[i];
#pragma unroll
      for (int i = 0; i < 4; ++i) *(bf16x8*)(Vs + (vrow0 + 64 * i) * 64 + voff) = vreg[i];
      __syncthreads();
    }
  }
  // ---- stats + direct unnormalized partial-O stores (64B runs per quad) ----
  size_t sbase = ((size_t)kh * BB + b) * NSP + n0;
  if (quad == 0) {
    pm[sbase + w * 16 + l16] = m_run;
    pl[sbase + w * 16 + l16] = l_run;
  }
  float* ob = po + ((size_t)kh * BB + b) * CCH * NSP;
#pragma unroll
  for (int cb = 0; cb < 16; ++cb)
#pragma unroll
    for (int r = 0; r < 4; ++r)
      ob[(size_t)(cb * 16 + quad * 4 + r) * NSP + n0 + w * 16 + l16] = accO[cb][r];
}

// ---------------- proj (+fused merge) + residual + /sqrt(2) ----------------
__global__ __launch_bounds__(256) void proj_kernel(
    const float* __restrict__ po, const float* __restrict__ pm,
    const float* __restrict__ pl, const float* __restrict__ Wp,
    const float* __restrict__ bp, const float* __restrict__ x,
    float* __restrict__ out) {
  __shared__ __align__(16) float Ws[32][64];
  __shared__ __align__(16) float Hs[32][64];
  __shared__ float w0s[64], w1s[64];
  int n0 = blockIdx.x * 64;
  int d0 = blockIdx.y * 64;
  int b = blockIdx.z;
  int tid = threadIdx.x;
  if (tid < 64) {
    size_t s0 = (size_t)b * NSP + n0 + tid;
    size_t s1 = ((size_t)BB + b) * NSP + n0 + tid;
    float m0 = pm[s0], m1 = pm[s1];
    float M = fmaxf(m0, m1);
    float a0 = __expf(m0 - M), a1 = __expf(m1 - M);
    float L = pl[s0] * a0 + pl[s1] * a1;
    float linv = 1.f / L;
    w0s[tid] = a0 * linv;
    w1s[tid] = a1 * linv;
  }
  const float* p0 = po + (size_t)b * CCH * NSP;
  const float* p1 = po + ((size_t)BB + b) * CCH * NSP;
  int tx = tid & 15, ty = tid >> 4;
  int srow = tid >> 4, sc4 = tid & 15;
  float acc[4][4] = {};
  __syncthreads();
  float4 w0v = *(float4*)&w0s[sc4 * 4];
  float4 w1v = *(float4*)&w1s[sc4 * 4];
  for (int c0 = 0; c0 < CCH; c0 += 32) {
#pragma unroll
    for (int i = 0; i < 2; ++i) {
      int row = srow + 16 * i;
      *(float4*)&Ws[row][sc4 * 4] =
          *(const float4*)&Wp[(size_t)(c0 + row) * CCH + d0 + sc4 * 4];
      size_t off = (size_t)(c0 + row) * NSP + n0 + sc4 * 4;
      float4 h0 = *(const float4*)(p0 + off);
      float4 h1 = *(const float4*)(p1 + off);
      float4 hm;
      hm.x = h0.x * w0v.x + h1.x * w1v.x;
      hm.y = h0.y * w0v.y + h1.y * w1v.y;
      hm.z = h0.z * w0v.z + h1.z * w1v.z;
      hm.w = h0.w * w0v.w + h1.w * w1v.w;
      *(float4*)&Hs[row][sc4 * 4] = hm;
    }
    __syncthreads();
    for (int cc = 0; cc < 32; ++cc) {
      float4 w4 = *(const float4*)&Ws[cc][ty * 4];
      float4 h4 = *(const float4*)&Hs[cc][tx * 4];
      const float wr[4] = {w4.x, w4.y, w4.z, w4.w};
      const float hr[4] = {h4.x, h4.y, h4.z, h4.w};
#pragma unroll
      for (int i = 0; i < 4; ++i)
#pragma unroll
        for (int j = 0; j < 4; ++j) acc[i][j] += wr[i] * hr[j];
    }
    __syncthreads();
  }
#pragma unroll
  for (int i = 0; i < 4; ++i) {
    int d = d0 + ty * 4 + i;
    float bi = bp[d];
    size_t off = ((size_t)b * CCH + d) * NSP + n0 + tx * 4;
    float4 xr = *(const float4*)(x + off);
    float4 r;
    r.x = (acc[i][0] + bi + xr.x) * RSQRT2;
    r.y = (acc[i][1] + bi + xr.y) * RSQRT2;
    r.z = (acc[i][2] + bi + xr.z) * RSQRT2;
    r.w = (acc[i][3] + bi + xr.w) * RSQRT2;
    *(float4*)(out + off) = r;
  }
}

extern "C" void kernel_launch(void* const* d_in, const int* in_sizes, int n_in,
                              void* d_out, int out_size, void* d_ws, size_t ws_size,
                              hipStream_t stream) {
  const float* x  = (const float*)d_in[0];
  const float* gw = (const float*)d_in[1];
  const float* gb = (const float*)d_in[2];
  const float* Wq = (const float*)d_in[3];
  const float* bq = (const float*)d_in[4];
  const float* Wk = (const float*)d_in[5];
  const float* bk = (const float*)d_in[6];
  const float* Wv = (const float*)d_in[7];
  const float* bv = (const float*)d_in[8];
  const float* Wp = (const float*)d_in[9];
  const float* bp = (const float*)d_in[10];
  float* out = (float*)d_out;

  const size_t SZ = (size_t)BB * CCH * NSP;  // 4.19M elems
  float* h  = (float*)d_ws;                  // gn out (qkv input)
  short* qb = (short*)(h + SZ);              // bf16 [b][n][c], pre-scaled
  short* kb = qb + SZ;                       // bf16 [b][n][c]
  short* vb = kb + SZ;                       // bf16 [b][c][n]
  float* po = (float*)(vb + SZ);             // fp32 [2][b][c][n] partials
  float* pm = po + KSPLIT * SZ;              // [2][b][n]
  float* pl = pm + (size_t)KSPLIT * BB * NSP;

  gn_kernel<<<dim3(BB * 32), dim3(256), 0, stream>>>(x, gw, gb, h);
  qkv_kernel<<<dim3(64, 4, 12), dim3(256), 0, stream>>>(
      h, Wq, bq, Wk, bk, Wv, bv, qb, kb, vb);
  attn_kernel<<<dim3(256), dim3(512), 0, stream>>>(qb, kb, vb, po, pm, pl);
  proj_kernel<<<dim3(64, 4, BB), dim3(256), 0, stream>>>(po, pm, pl, Wp, bp, x, out);
}